// Round 6
// baseline (45744.977 us; speedup 1.0000x reference)
//
#include <hip/hip_runtime.h>
#include <cstdint>
#include <cstddef>

#define LSEQ 512
#define NBLK 256

typedef _Float16 f16;
typedef f16 f16x8 __attribute__((ext_vector_type(8)));
typedef float f32x4 __attribute__((ext_vector_type(4)));

#define MFMA16(a, b, c) __builtin_amdgcn_mfma_f32_16x16x32_f16(a, b, c, 0, 0, 0)

static __device__ __forceinline__ float sigm(float x){ return 1.f/(1.f+__expf(-x)); }
static __device__ __forceinline__ float tanh_f(float x){
    x = fminf(fmaxf(x,-15.f),15.f);
    float t = __expf(-2.f*x);
    return (1.f-t)/(1.f+t);
}
static __device__ __forceinline__ f16x8 cvt8(const float* s){
    float4 a = *(const float4*)s, b = *(const float4*)(s+4);
    f16x8 v = {(f16)a.x,(f16)a.y,(f16)a.z,(f16)a.w,(f16)b.x,(f16)b.y,(f16)b.z,(f16)b.w};
    return v;
}

// Grid barrier. All 256 blocks co-resident (1/CU forced by LDS+VGPR+bounds).
// Release fence = wbL2 (producer h stores reach IC); acquire fence = invL2
// (consumer refetches fresh). L2 holds nothing persistent (weights are in
// VGPRs), so the invalidate is cheap. Arrive/spin are relaxed IC atomics.
static __device__ __forceinline__ void grid_barrier(int* bar){
    __syncthreads();   // compiler drains vmcnt before s_barrier
    if (threadIdx.x == 0){
        __builtin_amdgcn_fence(__ATOMIC_RELEASE, "agent");   // wb L2
        int g = __hip_atomic_load(&bar[16], __ATOMIC_RELAXED, __HIP_MEMORY_SCOPE_AGENT);
        int old = __hip_atomic_fetch_add(&bar[0], 1, __ATOMIC_RELAXED, __HIP_MEMORY_SCOPE_AGENT);
        if (old == NBLK - 1){
            __hip_atomic_store(&bar[0], 0, __ATOMIC_RELAXED, __HIP_MEMORY_SCOPE_AGENT);
            __hip_atomic_store(&bar[16], g + 1, __ATOMIC_RELEASE, __HIP_MEMORY_SCOPE_AGENT);
        } else {
            while (__hip_atomic_load(&bar[16], __ATOMIC_RELAXED, __HIP_MEMORY_SCOPE_AGENT) == g)
                __builtin_amdgcn_s_sleep(1);
        }
        __builtin_amdgcn_fence(__ATOMIC_ACQUIRE, "agent");   // inv L2
    }
    __syncthreads();
}

// 256 identical blocks: (mh = blk>>7) m-half, (nb = blk&127) 8 j-cols x 4 gates
// for BOTH layers. Waves: tt = wav>>1 (gate-pair tile), kh = wav&1 (K-half).
// B0/B1 weight fragments VGPR-resident. h planes in A-frag layout
// [kc8 128][m 256][8]; staged m-half chunks (8 kc8 x 128 m, 16KB, db) in LDS.
__global__ void __launch_bounds__(256, 1) lstm_persist(
    const float* __restrict__ seq,
    const float* __restrict__ Wih0, const float* __restrict__ Whh0,
    const float* __restrict__ bih0, const float* __restrict__ bhh0,
    const float* __restrict__ Wih1, const float* __restrict__ Whh1,
    const float* __restrict__ bih1, const float* __restrict__ bhh1,
    const float* __restrict__ linW, const float* __restrict__ linb,
    f16* __restrict__ A0, f16* __restrict__ A1, float* __restrict__ out,
    int* __restrict__ bar)
{
    __shared__ char pool[33024] __attribute__((aligned(16))); // staging (2x16.5KB) / acc (32KB)
    __shared__ float ldsX[768];
    __shared__ float ldsWx[192];
    __shared__ float ldsBias[64];

    const int tid = threadIdx.x, lane = tid & 63, wav = tid >> 6;
    const int quad = lane >> 4, l15 = lane & 15;
    const int tt = wav >> 1, kh = wav & 1;
    const int blk = blockIdx.x;
    const int nb = blk & 127, mh = blk >> 7;
    const int j0 = nb * 8, m0 = mh * 128;
    constexpr int ASZ = 128 * 256 * 8;

    // ---- one-time init: bias + input-proj weights into LDS ----
    if (tid < 64){
        int g = (tid & 31) >> 3, j = tid & 7;
        int R = g * 1024 + j0 + j;
        ldsBias[tid] = (tid < 32) ? (bih0[R] + bhh0[R]) : (bih1[R] + bhh1[R]);
    }
    if (tid < 192){
        int row = tid / 6, i = tid - row * 6;
        int R = (row >> 3) * 1024 + j0 + (row & 7);
        ldsWx[tid] = Wih0[(size_t)R * 6 + i];
    }

    // ---- weights into VGPRs (fp16 frags) ----
    // B row for lane: n = l15 -> gate 2*tt + (l15>>3), col j0 + (l15&7)
    const int brow = (2 * tt + (l15 >> 3)) * 1024 + j0 + (l15 & 7);
    f16x8 b1[32], b0[16];
    {
        const float* W1 = kh ? Whh1 : Wih1;          // L1 K-half kh
        const float* w1p = W1 + (size_t)brow * 1024 + quad * 8;
        #pragma unroll
        for (int kw = 0; kw < 32; ++kw) b1[kw] = cvt8(w1p + kw * 32);
        // L0: wave kh takes kwins of parity kh: k = (2i+kh)*32 + quad*8
        const float* w0p = Whh0 + (size_t)brow * 1024 + quad * 8 + kh * 32;
        #pragma unroll
        for (int i = 0; i < 16; ++i) b0[i] = cvt8(w0p + i * 64);
    }

    float c0reg[4] = {0,0,0,0}, c1reg[4] = {0,0,0,0};
    const int ej = tid & 7, emg = tid >> 3;          // epilogue: j, m-group
    const int mt_ = emg >> 2, q_ = emg & 3;
    float* ldsAcc = (float*)pool;

    for (int p = 0; p <= LSEQ; ++p){
        const f16* A0r = A0 + (size_t)((p + 1) & 1) * ASZ;   // h0[p-1]
        const f16* A1r = A1 + (size_t)(p & 1) * ASZ;         // h1[p-2]
        f16* Aw0 = A0 + (size_t)(p & 1) * ASZ;               // h0[p]
        f16* Aw1 = A1 + (size_t)((p + 1) & 1) * ASZ;         // h1[p-1]

        if (p < LSEQ){
            const float* xp = seq + ((size_t)p * 256 + m0) * 6;
            for (int i = tid; i < 768; i += 256) ldsX[i] = xp[i];
        }

        f32x4 acc0[8], acc1[8];
        #pragma unroll
        for (int i = 0; i < 8; ++i){ acc0[i] = (f32x4){0,0,0,0}; acc1[i] = (f32x4){0,0,0,0}; }

        uint4 st[4];
        #pragma unroll
        for (int i = 0; i < 4; ++i){
            int flat = i * 256 + tid, kl = flat >> 7, ml = flat & 127;
            st[i] = *(const uint4*)(A0r + ((size_t)kl * 256 + m0 + ml) * 8);
        }

        // 32 chunks: 0..15 = h0 plane, 16..31 = h1 plane. 8 kc8 x 128 m each.
        #pragma unroll
        for (int c = 0; c < 32; ++c){
            __syncthreads();
            char* dst = pool + (c & 1) * 16512;
            #pragma unroll
            for (int i = 0; i < 4; ++i){
                int flat = i * 256 + tid, kl = flat >> 7, ml = flat & 127;
                *(uint4*)(dst + kl * 2064 + ml * 16) = st[i];
            }
            __syncthreads();
            if (c < 31){
                const f16* plane = (c + 1 < 16) ? A0r : A1r;
                int cc = (c + 1 < 16) ? (c + 1) : (c + 1 - 16);
                #pragma unroll
                for (int i = 0; i < 4; ++i){
                    int flat = i * 256 + tid, kl = flat >> 7, ml = flat & 127;
                    st[i] = *(const uint4*)(plane + ((size_t)(cc * 8 + kl) * 256 + m0 + ml) * 8);
                }
            }
            const char* la = pool + (c & 1) * 16512;
            if (c < 16){
                if (kh == 0){
                    #pragma unroll
                    for (int mt = 0; mt < 8; ++mt){
                        f16x8 a0 = *(const f16x8*)(la + quad * 2064 + (mt * 16 + l15) * 16);
                        f16x8 a1 = *(const f16x8*)(la + (4 + quad) * 2064 + (mt * 16 + l15) * 16);
                        acc1[mt] = MFMA16(a0, b1[2 * c], acc1[mt]);
                        acc1[mt] = MFMA16(a1, b1[2 * c + 1], acc1[mt]);
                        acc0[mt] = MFMA16(a0, b0[c], acc0[mt]);
                    }
                } else {
                    #pragma unroll
                    for (int mt = 0; mt < 8; ++mt){
                        f16x8 a1 = *(const f16x8*)(la + (4 + quad) * 2064 + (mt * 16 + l15) * 16);
                        acc0[mt] = MFMA16(a1, b0[c], acc0[mt]);
                    }
                }
            } else {
                if (kh == 1){
                    const int cc = c - 16;
                    #pragma unroll
                    for (int mt = 0; mt < 8; ++mt){
                        f16x8 a0 = *(const f16x8*)(la + quad * 2064 + (mt * 16 + l15) * 16);
                        f16x8 a1 = *(const f16x8*)(la + (4 + quad) * 2064 + (mt * 16 + l15) * 16);
                        acc1[mt] = MFMA16(a0, b1[2 * cc], acc1[mt]);
                        acc1[mt] = MFMA16(a1, b1[2 * cc + 1], acc1[mt]);
                    }
                }
            }
        }

        // ---- L0 epilogue (skip at p==512) ----
        if (p < LSEQ){
            __syncthreads();
            #pragma unroll
            for (int mt = 0; mt < 8; ++mt)
                *(f32x4*)(ldsAcc + ((wav * 8 + mt) * 64 + lane) * 4) = acc0[mt];
            __syncthreads();
            #pragma unroll
            for (int ii = 0; ii < 4; ++ii){
                const int ml = emg * 4 + ii;
                float gv[4];
                #pragma unroll
                for (int g = 0; g < 4; ++g){
                    int lidx = q_ * 16 + (g & 1) * 8 + ej;
                    float v = ldsAcc[((((g >> 1) * 2 + 0) * 8 + mt_) * 64 + lidx) * 4 + ii]
                            + ldsAcc[((((g >> 1) * 2 + 1) * 8 + mt_) * 64 + lidx) * 4 + ii];
                    float xv = 0.f;
                    #pragma unroll
                    for (int i = 0; i < 6; ++i) xv += ldsX[ml * 6 + i] * ldsWx[(g * 8 + ej) * 6 + i];
                    gv[g] = v + ldsBias[g * 8 + ej] + xv;
                }
                float I = sigm(gv[0]), F = sigm(gv[1]), G = tanh_f(gv[2]), O = sigm(gv[3]);
                float cn = F * c0reg[ii] + I * G;
                c0reg[ii] = cn;
                float h = O * tanh_f(cn);
                Aw0[((size_t)nb * 256 + m0 + ml) * 8 + ej] = (f16)h;
            }
        }
        // ---- L1 epilogue (skip at p==0) ----
        if (p >= 1){
            __syncthreads();
            #pragma unroll
            for (int mt = 0; mt < 8; ++mt)
                *(f32x4*)(ldsAcc + ((wav * 8 + mt) * 64 + lane) * 4) = acc1[mt];
            __syncthreads();
            #pragma unroll
            for (int ii = 0; ii < 4; ++ii){
                const int ml = emg * 4 + ii;
                float gv[4];
                #pragma unroll
                for (int g = 0; g < 4; ++g){
                    int lidx = q_ * 16 + (g & 1) * 8 + ej;
                    float v = ldsAcc[((((g >> 1) * 2 + 0) * 8 + mt_) * 64 + lidx) * 4 + ii]
                            + ldsAcc[((((g >> 1) * 2 + 1) * 8 + mt_) * 64 + lidx) * 4 + ii];
                    gv[g] = v + ldsBias[32 + g * 8 + ej];
                }
                float I = sigm(gv[0]), F = sigm(gv[1]), G = tanh_f(gv[2]), O = sigm(gv[3]);
                float cn = F * c1reg[ii] + I * G;
                c1reg[ii] = cn;
                float h = O * tanh_f(cn);
                Aw1[((size_t)nb * 256 + m0 + ml) * 8 + ej] = (f16)h;
            }
        }
        grid_barrier(bar);
    }

    // ---- final linear on h1[511] (parity 1); block b -> out[b] ----
    if (wav == 0){
        const f16* hp = A1 + (size_t)ASZ;
        float s = 0.f;
        #pragma unroll
        for (int u = 0; u < 2; ++u){
            int kc = u * 64 + lane;
            f16x8 hv = *(const f16x8*)(hp + ((size_t)kc * 256 + blk) * 8);
            #pragma unroll
            for (int j = 0; j < 8; ++j) s += (float)hv[j] * linW[kc * 8 + j];
        }
        #pragma unroll
        for (int m = 32; m >= 1; m >>= 1) s += __shfl_xor(s, m, 64);
        if (lane == 0) out[blk] = s + linb[0];
    }
}

extern "C" void kernel_launch(void* const* d_in, const int* in_sizes, int n_in,
                              void* d_out, int out_size, void* d_ws, size_t ws_size,
                              hipStream_t stream)
{
    (void)in_sizes; (void)n_in; (void)out_size; (void)ws_size;
    const float* seq  = (const float*)d_in[0];
    const float* Wih0 = (const float*)d_in[1];
    const float* Whh0 = (const float*)d_in[2];
    const float* bih0 = (const float*)d_in[3];
    const float* bhh0 = (const float*)d_in[4];
    const float* Wih1 = (const float*)d_in[5];
    const float* Whh1 = (const float*)d_in[6];
    const float* bih1 = (const float*)d_in[7];
    const float* bhh1 = (const float*)d_in[8];
    const float* linW = (const float*)d_in[9];
    const float* linb = (const float*)d_in[10];
    float* outp = (float*)d_out;

    char* ws = (char*)d_ws;
    f16* A0p = (f16*)ws;                      // [2][128][256][8] = 1 MB
    f16* A1p = (f16*)(ws + (1 << 20));        // 1 MB
    int* bar = (int*)(ws + (2 << 20));        // barrier state

    hipMemsetAsync(ws, 0, 2 << 20, stream);   // zero h parity planes
    hipMemsetAsync(bar, 0, 256, stream);      // zero barrier

    lstm_persist<<<dim3(NBLK), dim3(256), 0, stream>>>(
        seq, Wih0, Whh0, bih0, bhh0, Wih1, Whh1, bih1, bhh1, linW, linb,
        A0p, A1p, outp, bar);
}

// Round 7
// 32734.943 us; speedup vs baseline: 1.3974x; 1.3974x over previous
//
#include <hip/hip_runtime.h>
#include <cstdint>
#include <cstddef>

#define LSEQ 512
#define NBLK 256

typedef _Float16 f16;
typedef f16 f16x8 __attribute__((ext_vector_type(8)));
typedef float f32x4 __attribute__((ext_vector_type(4)));
typedef unsigned long long u64t;

#define MFMA16(a, b, c) __builtin_amdgcn_mfma_f32_16x16x32_f16(a, b, c, 0, 0, 0)

static __device__ __forceinline__ float sigm(float x){ return 1.f/(1.f+__expf(-x)); }
static __device__ __forceinline__ float tanh_f(float x){
    x = fminf(fmaxf(x,-15.f),15.f);
    float t = __expf(-2.f*x);
    return (1.f-t)/(1.f+t);
}
static __device__ __forceinline__ f16x8 cvt8(const float* s){
    float4 a = *(const float4*)s, b = *(const float4*)(s+4);
    f16x8 v = {(f16)a.x,(f16)a.y,(f16)a.z,(f16)a.w,(f16)b.x,(f16)b.y,(f16)b.z,(f16)b.w};
    return v;
}
// IC-coherent (agent-scope) 8B ops: plain coalescable vector mem ops with
// cache-bypass bits. No fences needed anywhere.
static __device__ __forceinline__ u64t hload(const u64t* p){
    return __hip_atomic_load(p, __ATOMIC_RELAXED, __HIP_MEMORY_SCOPE_AGENT);
}
static __device__ __forceinline__ void hstore(u64t* p, u64t v){
    __hip_atomic_store(p, v, __ATOMIC_RELAXED, __HIP_MEMORY_SCOPE_AGENT);
}
union U64F16 { u64t q; f16 h[4]; };
union U2F16x8 { u64t q[2]; f16x8 v; uint4 u4; };

// Fence-free grid barrier. Each wave drains its own vmem (stores acked at IC)
// before s_barrier; tid0 then does ONE relaxed IC add; spinners poll relaxed.
// Zero cache-maintenance instructions.
static __device__ __forceinline__ void grid_barrier(int* bar){
    __builtin_amdgcn_s_waitcnt(0x0f70);   // vmcnt(0)
    __syncthreads();
    if (threadIdx.x == 0){
        int g = __hip_atomic_load(&bar[32], __ATOMIC_RELAXED, __HIP_MEMORY_SCOPE_AGENT);
        int old = __hip_atomic_fetch_add(&bar[0], 1, __ATOMIC_RELAXED, __HIP_MEMORY_SCOPE_AGENT);
        if (old == NBLK - 1){
            __hip_atomic_store(&bar[0], 0, __ATOMIC_RELAXED, __HIP_MEMORY_SCOPE_AGENT);
            __hip_atomic_store(&bar[32], g + 1, __ATOMIC_RELAXED, __HIP_MEMORY_SCOPE_AGENT);
        } else {
            while (__hip_atomic_load(&bar[32], __ATOMIC_RELAXED, __HIP_MEMORY_SCOPE_AGENT) == g)
                __builtin_amdgcn_s_sleep(2);
        }
    }
    __syncthreads();
}

// Partition: 256 blocks = (mh 2) x (nb 128). Block owns m-half (128 rows) x
// 8 j-cols x 4 gates (=32 gate-cols) of BOTH layers. Waves: 4-way K-interleave
// (wave w owns kw with kw%4==w, kw = 32-k groups over combined K: h0|h1).
// Weights VGPR-resident fp16 frags. h planes [kc8 128][m 256][8] fp16,
// exchanged via relaxed agent atomics (IC-coherent).
__global__ void __launch_bounds__(256, 1) lstm_persist(
    const float* __restrict__ seq,
    const float* __restrict__ Wih0, const float* __restrict__ Whh0,
    const float* __restrict__ bih0, const float* __restrict__ bhh0,
    const float* __restrict__ Wih1, const float* __restrict__ Whh1,
    const float* __restrict__ bih1, const float* __restrict__ bhh1,
    const float* __restrict__ linW, const float* __restrict__ linb,
    f16* __restrict__ A0, f16* __restrict__ A1, float* __restrict__ out,
    int* __restrict__ bar)
{
    __shared__ char  pool[36864] __attribute__((aligned(16)));
    __shared__ float ldsX[768];
    __shared__ float ldsWx[192];
    __shared__ float ldsBias[64];

    const int tid = threadIdx.x, lane = tid & 63, wav = tid >> 6;
    const int quad = lane >> 4, l15 = lane & 15;
    const int uu = wav & 1;                   // kw-in-chunk parity this wave owns
    const int blk = blockIdx.x;
    const int nb = blk & 127, mh = blk >> 7;
    const int j0 = nb * 8, m0 = mh * 128;
    constexpr int ASZ = 128 * 256 * 8;        // halfs per parity plane

    // ---- one-time init ----
    if (tid < 64){
        int g = (tid & 31) >> 3, j = tid & 7;
        int R = g * 1024 + j0 + j;
        ldsBias[tid] = (tid < 32) ? (bih0[R] + bhh0[R]) : (bih1[R] + bhh1[R]);
    }
    if (tid < 192){
        int row = tid / 6, i = tid - row * 6;
        int R = (row >> 3) * 1024 + j0 + (row & 7);
        ldsWx[tid] = Wih0[(size_t)R * 6 + i];
    }
    // weight frags: B[n=l15][k=quad*8+j]; row R = (2nt + l15>>3)*1024 + j0 + (l15&7)
    f16x8 w1[16][2], w0[8][2];
    {
        size_t R[2];
        #pragma unroll
        for (int nt = 0; nt < 2; ++nt)
            R[nt] = (size_t)((2*nt + (l15 >> 3)) * 1024 + j0 + (l15 & 7)) * 1024;
        #pragma unroll
        for (int i = 0; i < 16; ++i){
            int kw = 4*i + wav;
            int kc = kw * 32 + quad * 8;
            const float* base = (i < 8) ? (Wih1 + kc) : (Whh1 + (kc - 1024));
            #pragma unroll
            for (int nt = 0; nt < 2; ++nt) w1[i][nt] = cvt8(base + R[nt]);
        }
        #pragma unroll
        for (int i = 0; i < 8; ++i){
            int kc = (4*i + wav) * 32 + quad * 8;
            #pragma unroll
            for (int nt = 0; nt < 2; ++nt) w0[i][nt] = cvt8(Whh0 + R[nt] + kc);
        }
    }

    // staging map: thread -> (ml = tid>>1, half h = tid&1): 8 u64 = rows kc8base+4h..+4 of row ml
    const int sml = tid >> 1, sh = tid & 1;
    // epilogue map: thread -> (row = tid>>1, j4 = (tid&1)*4)
    const int erow = tid >> 1, ej4 = (tid & 1) * 4;
    const int emt = erow >> 4, eq4r = erow & 15;
    float c0reg[4] = {0,0,0,0}, c1reg[4] = {0,0,0,0};
    float* buf2 = (float*)(pool + 16384);

    u64t stA[8], stB[8];

    for (int p = 0; p <= LSEQ; ++p){
        const u64t* P0 = (const u64t*)(A0 + (size_t)((p + 1) & 1) * ASZ); // h0[p-1]
        const u64t* P1 = (const u64t*)(A1 + (size_t)(p & 1) * ASZ);      // h1[p-2]
        u64t* W0p = (u64t*)(A0 + (size_t)(p & 1) * ASZ);                 // h0[p]
        u64t* W1p = (u64t*)(A1 + (size_t)((p + 1) & 1) * ASZ);           // h1[p-1]

        // prefetch chunks 0,1 (h0 plane)
        #pragma unroll
        for (int i = 0; i < 8; ++i){
            size_t b = ((size_t)(4*sh + (i>>1))*256 + m0 + sml)*2 + (i&1);
            stA[i] = hload(P0 + b);
        }
        #pragma unroll
        for (int i = 0; i < 8; ++i){
            size_t b = ((size_t)(8 + 4*sh + (i>>1))*256 + m0 + sml)*2 + (i&1);
            stB[i] = hload(P0 + b);
        }
        if (p < LSEQ){
            const float* xp = seq + ((size_t)p * 256 + m0) * 6;
            for (int i = tid; i < 768; i += 256) ldsX[i] = xp[i];
        }

        f32x4 acc0[8][2], acc1[8][2];
        #pragma unroll
        for (int a = 0; a < 8; ++a)
            #pragma unroll
            for (int b = 0; b < 2; ++b){ acc0[a][b] = (f32x4){0,0,0,0}; acc1[a][b] = (f32x4){0,0,0,0}; }

        #pragma unroll 1
        for (int cc = 0; cc < 16; ++cc){
            // ---- chunk 2cc (waves 0,1) into buf0 ----
            __syncthreads();
            {
                char* dst = pool + sml*144 + sh*64;
                #pragma unroll
                for (int i = 0; i < 4; ++i){
                    U2F16x8 t; t.q[0] = stA[2*i]; t.q[1] = stA[2*i+1];
                    *(uint4*)(dst + i*16) = t.u4;
                }
            }
            __syncthreads();
            if (cc < 15){                         // prefetch chunk 2cc+2
                int n = 2*cc + 2;
                const u64t* P = (n < 16) ? P0 : P1;
                int kb = (n < 16) ? 8*n : 8*(n-16);
                #pragma unroll
                for (int i = 0; i < 8; ++i){
                    size_t b = ((size_t)(kb + 4*sh + (i>>1))*256 + m0 + sml)*2 + (i&1);
                    stA[i] = hload(P + b);
                }
            }
            if (wav < 2){
                const char* la = pool;
                #pragma unroll
                for (int mt = 0; mt < 8; ++mt){
                    f16x8 af = *(const f16x8*)(la + (mt*16 + l15)*144 + (4*uu + quad)*16);
                    #pragma unroll
                    for (int nt = 0; nt < 2; ++nt)
                        acc1[mt][nt] = MFMA16(af, w1[cc][nt], acc1[mt][nt]);
                    if (cc < 8)
                        #pragma unroll
                        for (int nt = 0; nt < 2; ++nt)
                            acc0[mt][nt] = MFMA16(af, w0[cc < 8 ? cc : 0][nt], acc0[mt][nt]);
                }
            }
            // ---- chunk 2cc+1 (waves 2,3) into buf1 ----
            __syncthreads();
            {
                char* dst = pool + 18432 + sml*144 + sh*64;
                #pragma unroll
                for (int i = 0; i < 4; ++i){
                    U2F16x8 t; t.q[0] = stB[2*i]; t.q[1] = stB[2*i+1];
                    *(uint4*)(dst + i*16) = t.u4;
                }
            }
            __syncthreads();
            if (cc < 15){                         // prefetch chunk 2cc+3
                int n = 2*cc + 3;
                const u64t* P = (n < 16) ? P0 : P1;
                int kb = (n < 16) ? 8*n : 8*(n-16);
                #pragma unroll
                for (int i = 0; i < 8; ++i){
                    size_t b = ((size_t)(kb + 4*sh + (i>>1))*256 + m0 + sml)*2 + (i&1);
                    stB[i] = hload(P + b);
                }
            }
            if (wav >= 2){
                const char* la = pool + 18432;
                #pragma unroll
                for (int mt = 0; mt < 8; ++mt){
                    f16x8 af = *(const f16x8*)(la + (mt*16 + l15)*144 + (4*uu + quad)*16);
                    #pragma unroll
                    for (int nt = 0; nt < 2; ++nt)
                        acc1[mt][nt] = MFMA16(af, w1[cc][nt], acc1[mt][nt]);
                    if (cc < 8)
                        #pragma unroll
                        for (int nt = 0; nt < 2; ++nt)
                            acc0[mt][nt] = MFMA16(af, w0[cc < 8 ? cc : 0][nt], acc0[mt][nt]);
                }
            }
        }

        // ================= epilogues =================
        #pragma unroll
        for (int layer = 0; layer < 2; ++layer){
            if (layer == 0 && p >= LSEQ) continue;
            if (layer == 1 && p < 1) continue;
            f32x4 (*acc)[2] = layer ? acc1 : acc0;

            // cross-wave K-reduction: 1,3 dump -> 0,2 add -> 2 dumps -> 0 adds
            __syncthreads();
            if (uu == 1){
                int slot = wav >> 1;
                #pragma unroll
                for (int mt = 0; mt < 8; ++mt)
                    #pragma unroll
                    for (int nt = 0; nt < 2; ++nt)
                        *(f32x4*)(pool + (((slot*8+mt)*2+nt)*64 + lane)*16) = acc[mt][nt];
            }
            __syncthreads();
            if (uu == 0){
                int slot = wav >> 1;
                #pragma unroll
                for (int mt = 0; mt < 8; ++mt)
                    #pragma unroll
                    for (int nt = 0; nt < 2; ++nt)
                        acc[mt][nt] += *(const f32x4*)(pool + (((slot*8+mt)*2+nt)*64 + lane)*16);
            }
            __syncthreads();
            if (wav == 2){
                #pragma unroll
                for (int mt = 0; mt < 8; ++mt)
                    #pragma unroll
                    for (int nt = 0; nt < 2; ++nt)
                        *(f32x4*)(pool + ((mt*2+nt)*64 + lane)*16) = acc[mt][nt];
            }
            __syncthreads();
            if (wav == 0){
                #pragma unroll
                for (int mt = 0; mt < 8; ++mt)
                    #pragma unroll
                    for (int nt = 0; nt < 2; ++nt){
                        f32x4 v = acc[mt][nt] + *(const f32x4*)(pool + ((mt*2+nt)*64 + lane)*16);
                        int gate = 2*nt + (l15 >> 3), j = l15 & 7;
                        #pragma unroll
                        for (int r = 0; r < 4; ++r)
                            buf2[gate*1161 + mt*145 + (quad*4 + r)*9 + j] = v[r];
                    }
            }
            __syncthreads();

            // gather + LSTM pointwise + packed 8B h-store
            {
                float* creg = layer ? c1reg : c0reg;
                float xv[6];
                if (layer == 0)
                    #pragma unroll
                    for (int i = 0; i < 6; ++i) xv[i] = ldsX[erow*6 + i];
                U64F16 hv;
                #pragma unroll
                for (int jj = 0; jj < 4; ++jj){
                    int j = ej4 + jj;
                    float gv[4];
                    #pragma unroll
                    for (int g = 0; g < 4; ++g){
                        float v = buf2[g*1161 + emt*145 + eq4r*9 + j] + ldsBias[layer*32 + g*8 + j];
                        if (layer == 0)
                            #pragma unroll
                            for (int i = 0; i < 6; ++i) v += xv[i] * ldsWx[(g*8 + j)*6 + i];
                        gv[g] = v;
                    }
                    float I = sigm(gv[0]), F = sigm(gv[1]), G = tanh_f(gv[2]), O = sigm(gv[3]);
                    float cn = F * creg[jj] + I * G;
                    creg[jj] = cn;
                    hv.h[jj] = (f16)(O * tanh_f(cn));
                }
                u64t* Wp = layer ? W1p : W0p;
                hstore(Wp + ((size_t)nb*256 + m0 + erow)*2 + (tid & 1), hv.q);
            }
        }
        grid_barrier(bar);
    }

    // ---- final linear on h1[511] (plane 1); block b -> out[b] ----
    if (wav == 0){
        const u64t* hp = (const u64t*)(A1 + (size_t)ASZ);
        float s = 0.f;
        #pragma unroll
        for (int u = 0; u < 2; ++u){
            int kc = u*64 + lane;
            U2F16x8 t;
            size_t b = ((size_t)kc*256 + blk)*2;
            t.q[0] = hload(hp + b);
            t.q[1] = hload(hp + b + 1);
            #pragma unroll
            for (int j = 0; j < 8; ++j) s += (float)t.v[j] * linW[kc*8 + j];
        }
        #pragma unroll
        for (int m = 32; m >= 1; m >>= 1) s += __shfl_xor(s, m, 64);
        if (lane == 0) out[blk] = s + linb[0];
    }
}

extern "C" void kernel_launch(void* const* d_in, const int* in_sizes, int n_in,
                              void* d_out, int out_size, void* d_ws, size_t ws_size,
                              hipStream_t stream)
{
    (void)in_sizes; (void)n_in; (void)out_size; (void)ws_size;
    const float* seq  = (const float*)d_in[0];
    const float* Wih0 = (const float*)d_in[1];
    const float* Whh0 = (const float*)d_in[2];
    const float* bih0 = (const float*)d_in[3];
    const float* bhh0 = (const float*)d_in[4];
    const float* Wih1 = (const float*)d_in[5];
    const float* Whh1 = (const float*)d_in[6];
    const float* bih1 = (const float*)d_in[7];
    const float* bhh1 = (const float*)d_in[8];
    const float* linW = (const float*)d_in[9];
    const float* linb = (const float*)d_in[10];
    float* outp = (float*)d_out;

    char* ws = (char*)d_ws;
    f16* A0p = (f16*)ws;                      // [2][128][256][8] = 1 MB
    f16* A1p = (f16*)(ws + (1 << 20));        // 1 MB
    int* bar = (int*)(ws + (2 << 20));        // barrier state

    hipMemsetAsync(ws, 0, 2 << 20, stream);   // zero h parity planes
    hipMemsetAsync(bar, 0, 256, stream);      // zero barrier

    lstm_persist<<<dim3(NBLK), dim3(256), 0, stream>>>(
        seq, Wih0, Whh0, bih0, bhh0, Wih1, Whh1, bih1, bhh1, linW, linb,
        A0p, A1p, outp, bar);
}

// Round 9
// 18390.804 us; speedup vs baseline: 2.4874x; 1.7800x over previous
//
#include <hip/hip_runtime.h>
#include <cstdint>
#include <cstddef>

#define LSEQ 512
#define NBLK 192
#define ASZ (128*256*8)   // halfs per h parity plane (512 KB)

typedef _Float16 f16;
typedef f16 f16x8 __attribute__((ext_vector_type(8)));
typedef float f32x4 __attribute__((ext_vector_type(4)));
typedef int v4i __attribute__((ext_vector_type(4)));
typedef unsigned long long u64t;

#define MFMA16(a, b, c) __builtin_amdgcn_mfma_f32_16x16x32_f16(a, b, c, 0, 0, 0)

static __device__ __forceinline__ float sigm(float x){ return 1.f/(1.f+__expf(-x)); }
static __device__ __forceinline__ float tanh_f(float x){
    x = fminf(fmaxf(x,-15.f),15.f);
    float t = __expf(-2.f*x);
    return (1.f-t)/(1.f+t);
}
static __device__ __forceinline__ f16x8 cvt8(const float* s){
    float4 a = *(const float4*)s, b = *(const float4*)(s+4);
    f16x8 v = {(f16)a.x,(f16)a.y,(f16)a.z,(f16)a.w,(f16)b.x,(f16)b.y,(f16)b.z,(f16)b.w};
    return v;
}

// ---- IC-coherent 16B load: plain buffer load with SC0|SC1 (bypass L1+L2,
// served at the Infinity Cache = device coherence point). Compiler-managed
// waitcnts (no forced drain -> prefetch pipeline survives). aux 0x11 = SC0|SC1.
static __device__ __forceinline__ uint4 ic_load(const char* base, int voff){
    __amdgpu_buffer_rsrc_t srd =
        __builtin_amdgcn_make_buffer_rsrc((void*)base, (short)0, -1, 0x00020000);
    v4i r = __builtin_amdgcn_raw_buffer_load_b128(srd, voff, 0, 0x11);
    return __builtin_bit_cast(uint4, r);
}
// 8B IC-coherent atomic ops (h stores + final read + barrier) — R7-proven.
static __device__ __forceinline__ u64t hload(const u64t* p){
    return __hip_atomic_load(p, __ATOMIC_RELAXED, __HIP_MEMORY_SCOPE_AGENT);
}
static __device__ __forceinline__ void hstore(u64t* p, u64t v){
    __hip_atomic_store(p, v, __ATOMIC_RELAXED, __HIP_MEMORY_SCOPE_AGENT);
}
union U64F16 { u64t q; f16 h[4]; };
union U2F16x8 { u64t q[2]; f16x8 v; };

// Raw chunk barriers: keep vmcnt (prefetches) alive across s_barrier.
#define SYNC_RAW()  __builtin_amdgcn_s_barrier()
#define SYNC_LGKM() do { __builtin_amdgcn_s_waitcnt(0xC07F); __builtin_amdgcn_s_barrier(); } while(0)

// Fence-free grid barrier (R7): drain own vmem (stores acked at IC), one
// relaxed IC add, relaxed spin. No cache-maintenance instructions.
static __device__ __forceinline__ void grid_barrier(int* bar){
    __builtin_amdgcn_s_waitcnt(0x0f70);   // vmcnt(0)
    __syncthreads();
    if (threadIdx.x == 0){
        int g = __hip_atomic_load(&bar[32], __ATOMIC_RELAXED, __HIP_MEMORY_SCOPE_AGENT);
        int old = __hip_atomic_fetch_add(&bar[0], 1, __ATOMIC_RELAXED, __HIP_MEMORY_SCOPE_AGENT);
        if (old == NBLK - 1){
            __hip_atomic_store(&bar[0], 0, __ATOMIC_RELAXED, __HIP_MEMORY_SCOPE_AGENT);
            __hip_atomic_store(&bar[32], g + 1, __ATOMIC_RELAXED, __HIP_MEMORY_SCOPE_AGENT);
        } else {
            while (__hip_atomic_load(&bar[32], __ATOMIC_RELAXED, __HIP_MEMORY_SCOPE_AGENT) == g)
                __builtin_amdgcn_s_sleep(2);
        }
    }
    __syncthreads();
}

// Blocks 0..127: L1 (mh=blk>>6 m-half 128 rows, nb=blk&63 -> 16 j-cols x 4 gates).
// Blocks 128..191: L0 (all 256 rows, nb -> 16 j-cols x 4 gates).
// Waves: nh=wav&1 (col-half, 32 gate-cols), kh=wav>>1 (K-half).
// Weights VGPR-resident fp16 frags; h planes [kc8 128][m 256][8] fp16 via IC.
__global__ void __launch_bounds__(256, 1) lstm_persist(
    const float* __restrict__ seq,
    const float* __restrict__ Wih0, const float* __restrict__ Whh0,
    const float* __restrict__ bih0, const float* __restrict__ bhh0,
    const float* __restrict__ Wih1, const float* __restrict__ Whh1,
    const float* __restrict__ bih1, const float* __restrict__ bhh1,
    const float* __restrict__ linW, const float* __restrict__ linb,
    f16* __restrict__ A0, f16* __restrict__ A1, float* __restrict__ out,
    int* __restrict__ bar)
{
    __shared__ char  pool[34816] __attribute__((aligned(16)));
    __shared__ float ldsX[1536];
    __shared__ float ldsWx[384];
    __shared__ float ldsBias[64];
    float* poolf = (float*)pool;

    const int tid = threadIdx.x, lane = tid & 63, wav = tid >> 6;
    const int quad = lane >> 4, l15 = lane & 15;
    const int nh = wav & 1, kh = wav >> 1;
    const int blk = blockIdx.x;

    if (blk < 128){
        // ======================= L1 =======================
        const int mh = blk >> 6, nb = blk & 63;
        const int m0 = mh * 128, j0 = nb * 16;
        if (tid < 64){
            int R = (tid >> 4) * 1024 + j0 + (tid & 15);
            ldsBias[tid] = bih1[R] + bhh1[R];
        }
        // weights: w1[kg][nt], k = kh*1024 + kg*32 + quad*8 (kh=0 -> Wih1, kh=1 -> Whh1)
        f16x8 w1[32][2];
        {
            const float* Wsrc = kh ? Whh1 : Wih1;
            #pragma unroll
            for (int nt = 0; nt < 2; ++nt){
                int ct = nh * 32 + nt * 16 + l15;
                size_t Roff = (size_t)((ct >> 4) * 1024 + j0 + (ct & 15)) * 1024;
                #pragma unroll
                for (int kg = 0; kg < 32; ++kg)
                    w1[kg][nt] = cvt8(Wsrc + Roff + kg * 32 + quad * 8);
            }
        }
        float c1[8] = {0,0,0,0,0,0,0,0};

        for (int p = 0; p <= LSEQ; ++p){
            if (p >= 1){
                const char* P0 = (const char*)(A0 + (size_t)((p + 1) & 1) * ASZ); // h0[p-1]
                const char* P1 = (const char*)(A1 + (size_t)(p & 1) * ASZ);       // h1[p-2]
                u64t* W1p = (u64t*)(A1 + (size_t)((p + 1) & 1) * ASZ);            // h1[p-1]

                f32x4 acc[8][2];
                #pragma unroll
                for (int a = 0; a < 8; ++a){ acc[a][0] = (f32x4){0,0,0,0}; acc[a][1] = (f32x4){0,0,0,0}; }

                uint4 st[2][4];
                #pragma unroll
                for (int i = 0; i < 4; ++i){
                    int idx = i * 256 + tid, kc8l = idx >> 7, ml = idx & 127;
                    st[0][i] = ic_load(P0, ((kc8l) * 256 + m0 + ml) * 16);
                    st[1][i] = ic_load(P0, ((8 + kc8l) * 256 + m0 + ml) * 16);
                }
                #pragma unroll
                for (int c = 0; c < 32; ++c){
                    SYNC_RAW();                               // buf[c&1] readers (iter c-2) done
                    {
                        char* dst = pool + (c & 1) * 16512;
                        #pragma unroll
                        for (int i = 0; i < 4; ++i){
                            int idx = i * 256 + tid, kc8l = idx >> 7, ml = idx & 127;
                            *(uint4*)(dst + kc8l * 2064 + ml * 16) = st[c & 1][i];
                        }
                    }
                    SYNC_LGKM();                              // writes visible
                    if (c < 30){
                        const int n = c + 2;
                        const char* P = (n < 16) ? P0 : P1;
                        const int kb = (n < 16) ? n * 8 : (n - 16) * 8;
                        #pragma unroll
                        for (int i = 0; i < 4; ++i){
                            int idx = i * 256 + tid, kc8l = idx >> 7, ml = idx & 127;
                            st[c & 1][i] = ic_load(P, ((kb + kc8l) * 256 + m0 + ml) * 16);
                        }
                    }
                    if (kh == ((c < 16) ? 0 : 1)){
                        const char* la = pool + (c & 1) * 16512;
                        const int cl = (c < 16) ? c : c - 16;
                        #pragma unroll
                        for (int kgl = 0; kgl < 2; ++kgl){
                            const int ckg = cl * 2 + kgl;
                            #pragma unroll
                            for (int mt = 0; mt < 8; ++mt){
                                f16x8 af = *(const f16x8*)(la + (kgl * 4 + quad) * 2064 + (mt * 16 + l15) * 16);
                                acc[mt][0] = MFMA16(af, w1[ckg][0], acc[mt][0]);
                                acc[mt][1] = MFMA16(af, w1[ckg][1], acc[mt][1]);
                            }
                        }
                    }
                }
                // ---- epilogue: K-reduce (kh1 -> kh0) via LDS, gather, pointwise ----
                __syncthreads();
                if (kh == 1){
                    #pragma unroll
                    for (int mt = 0; mt < 8; ++mt)
                        #pragma unroll
                        for (int nt = 0; nt < 2; ++nt){
                            int ct = nh * 32 + nt * 16 + l15;
                            *(f32x4*)(poolf + ct * 132 + mt * 16 + quad * 4) = acc[mt][nt];
                        }
                }
                __syncthreads();
                if (kh == 0){
                    #pragma unroll
                    for (int mt = 0; mt < 8; ++mt)
                        #pragma unroll
                        for (int nt = 0; nt < 2; ++nt){
                            int ct = nh * 32 + nt * 16 + l15;
                            f32x4 v = acc[mt][nt] + *(const f32x4*)(poolf + ct * 132 + mt * 16 + quad * 4);
                            *(f32x4*)(poolf + ct * 132 + mt * 16 + quad * 4) = v;
                        }
                }
                __syncthreads();
                {
                    const int m = tid >> 1, jh = tid & 1;
                    float hq[8];
                    #pragma unroll
                    for (int jj = 0; jj < 8; ++jj){
                        int j = jh * 8 + jj;
                        float gv[4];
                        #pragma unroll
                        for (int g = 0; g < 4; ++g)
                            gv[g] = poolf[(g * 16 + j) * 132 + m] + ldsBias[g * 16 + j];
                        float I = sigm(gv[0]), F = sigm(gv[1]), G = tanh_f(gv[2]), O = sigm(gv[3]);
                        float cn = F * c1[jj] + I * G;
                        c1[jj] = cn;
                        hq[jj] = O * tanh_f(cn);
                    }
                    const int kc8 = nb * 2 + jh;
                    #pragma unroll
                    for (int q = 0; q < 2; ++q){
                        U64F16 v;
                        #pragma unroll
                        for (int w = 0; w < 4; ++w) v.h[w] = (f16)hq[q * 4 + w];
                        hstore(W1p + (size_t)(kc8 * 256 + m0 + m) * 2 + q, v.q);
                    }
                }
            }
            grid_barrier(bar);
        }
    } else {
        // ======================= L0 =======================
        const int nb0 = blk - 128;
        const int j0 = nb0 * 16;
        if (tid < 64){
            int R = (tid >> 4) * 1024 + j0 + (tid & 15);
            ldsBias[tid] = bih0[R] + bhh0[R];
        }
        for (int t = tid; t < 384; t += 256){
            int ct = t / 6, i = t - ct * 6;
            int R = (ct >> 4) * 1024 + j0 + (ct & 15);
            ldsWx[t] = Wih0[(size_t)R * 6 + i];
        }
        f16x8 w0[16][2];
        {
            #pragma unroll
            for (int nt = 0; nt < 2; ++nt){
                int ct = nh * 32 + nt * 16 + l15;
                size_t Roff = (size_t)((ct >> 4) * 1024 + j0 + (ct & 15)) * 1024;
                #pragma unroll
                for (int kg = 0; kg < 16; ++kg)
                    w0[kg][nt] = cvt8(Whh0 + Roff + kh * 512 + kg * 32 + quad * 8);
            }
        }
        float c0[16];
        #pragma unroll
        for (int i = 0; i < 16; ++i) c0[i] = 0.f;

        for (int p = 0; p <= LSEQ; ++p){
            if (p < LSEQ){
                const char* P0 = (const char*)(A0 + (size_t)((p + 1) & 1) * ASZ); // h0[p-1]
                u64t* W0p = (u64t*)(A0 + (size_t)(p & 1) * ASZ);                  // h0[p]
                {   // stage x[p]
                    const float2* xp = (const float2*)(seq + (size_t)p * 1536);
                    float2* xd = (float2*)ldsX;
                    for (int i = tid; i < 768; i += 256) xd[i] = xp[i];
                }
                f32x4 acc[16][2];
                #pragma unroll
                for (int a = 0; a < 16; ++a){ acc[a][0] = (f32x4){0,0,0,0}; acc[a][1] = (f32x4){0,0,0,0}; }

                uint4 st[2][4];
                #pragma unroll
                for (int i = 0; i < 4; ++i){
                    int idx = i * 256 + tid, kc8l = idx >> 8, ml = idx & 255;
                    st[0][i] = ic_load(P0, ((kc8l) * 256 + ml) * 16);
                    st[1][i] = ic_load(P0, ((4 + kc8l) * 256 + ml) * 16);
                }
                #pragma unroll
                for (int c = 0; c < 32; ++c){
                    SYNC_RAW();
                    {
                        char* dst = pool + (c & 1) * 16448;
                        #pragma unroll
                        for (int i = 0; i < 4; ++i){
                            int idx = i * 256 + tid, kc8l = idx >> 8, ml = idx & 255;
                            *(uint4*)(dst + kc8l * 4112 + ml * 16) = st[c & 1][i];
                        }
                    }
                    SYNC_LGKM();
                    if (c < 30){
                        const int kb = (c + 2) * 4;
                        #pragma unroll
                        for (int i = 0; i < 4; ++i){
                            int idx = i * 256 + tid, kc8l = idx >> 8, ml = idx & 255;
                            st[c & 1][i] = ic_load(P0, ((kb + kc8l) * 256 + ml) * 16);
                        }
                    }
                    if (kh == (c >> 4)){
                        const char* la = pool + (c & 1) * 16448;
                        const int ckg = c & 15;
                        #pragma unroll
                        for (int mt = 0; mt < 16; ++mt){
                            f16x8 af = *(const f16x8*)(la + quad * 4112 + (mt * 16 + l15) * 16);
                            acc[mt][0] = MFMA16(af, w0[ckg][0], acc[mt][0]);
                            acc[mt][1] = MFMA16(af, w0[ckg][1], acc[mt][1]);
                        }
                    }
                }
                // ---- epilogue: two m-half rounds ----
                #pragma unroll
                for (int hh = 0; hh < 2; ++hh){
                    __syncthreads();
                    if (kh == 1){
                        #pragma unroll
                        for (int mt = 8 * hh; mt < 8 * hh + 8; ++mt)
                            #pragma unroll
                            for (int nt = 0; nt < 2; ++nt){
                                int ct = nh * 32 + nt * 16 + l15;
                                *(f32x4*)(poolf + ct * 132 + (mt - 8 * hh) * 16 + quad * 4) = acc[mt][nt];
                            }
                    }
                    __syncthreads();
                    if (kh == 0){
                        #pragma unroll
                        for (int mt = 8 * hh; mt < 8 * hh + 8; ++mt)
                            #pragma unroll
                            for (int nt = 0; nt < 2; ++nt){
                                int ct = nh * 32 + nt * 16 + l15;
                                f32x4 v = acc[mt][nt] + *(const f32x4*)(poolf + ct * 132 + (mt - 8 * hh) * 16 + quad * 4);
                                *(f32x4*)(poolf + ct * 132 + (mt - 8 * hh) * 16 + quad * 4) = v;
                            }
                    }
                    __syncthreads();
                    {
                        const int ml = tid >> 1, jh = tid & 1;
                        const int ma = 128 * hh + ml;
                        float xv[6];
                        #pragma unroll
                        for (int i = 0; i < 6; ++i) xv[i] = ldsX[ma * 6 + i];
                        float hq[8];
                        #pragma unroll
                        for (int jj = 0; jj < 8; ++jj){
                            int j = jh * 8 + jj;
                            float gv[4];
                            #pragma unroll
                            for (int g = 0; g < 4; ++g){
                                float v = poolf[(g * 16 + j) * 132 + ml] + ldsBias[g * 16 + j];
                                #pragma unroll
                                for (int i = 0; i < 6; ++i) v += xv[i] * ldsWx[(g * 16 + j) * 6 + i];
                                gv[g] = v;
                            }
                            float I = sigm(gv[0]), F = sigm(gv[1]), G = tanh_f(gv[2]), O = sigm(gv[3]);
                            float cn = F * c0[hh * 8 + jj] + I * G;
                            c0[hh * 8 + jj] = cn;
                            hq[jj] = O * tanh_f(cn);
                        }
                        const int kc8 = nb0 * 2 + jh;
                        #pragma unroll
                        for (int q = 0; q < 2; ++q){
                            U64F16 v;
                            #pragma unroll
                            for (int w = 0; w < 4; ++w) v.h[w] = (f16)hq[q * 4 + w];
                            hstore(W0p + (size_t)(kc8 * 256 + ma) * 2 + q, v.q);
                        }
                    }
                }
            }
            grid_barrier(bar);
        }
        // ---- final linear on h1[511] (plane parity 1) ----
        {
            const u64t* hp = (const u64t*)(A1 + (size_t)ASZ);
            int n = nb0 * 4 + wav;
            float s = 0.f;
            #pragma unroll
            for (int u = 0; u < 2; ++u){
                int kc = u * 64 + lane;
                U2F16x8 t;
                t.q[0] = hload(hp + (size_t)(kc * 256 + n) * 2);
                t.q[1] = hload(hp + (size_t)(kc * 256 + n) * 2 + 1);
                #pragma unroll
                for (int j = 0; j < 8; ++j) s += (float)t.v[j] * linW[kc * 8 + j];
            }
            #pragma unroll
            for (int m = 32; m >= 1; m >>= 1) s += __shfl_xor(s, m, 64);
            if (lane == 0) out[n] = s + linb[0];
        }
    }
}

extern "C" void kernel_launch(void* const* d_in, const int* in_sizes, int n_in,
                              void* d_out, int out_size, void* d_ws, size_t ws_size,
                              hipStream_t stream)
{
    (void)in_sizes; (void)n_in; (void)out_size; (void)ws_size;
    const float* seq  = (const float*)d_in[0];
    const float* Wih0 = (const float*)d_in[1];
    const float* Whh0 = (const float*)d_in[2];
    const float* bih0 = (const float*)d_in[3];
    const float* bhh0 = (const float*)d_in[4];
    const float* Wih1 = (const float*)d_in[5];
    const float* Whh1 = (const float*)d_in[6];
    const float* bih1 = (const float*)d_in[7];
    const float* bhh1 = (const float*)d_in[8];
    const float* linW = (const float*)d_in[9];
    const float* linb = (const float*)d_in[10];
    float* outp = (float*)d_out;

    char* ws = (char*)d_ws;
    f16* A0p = (f16*)ws;                      // h0: [2][128 kc8][256 m][8] = 1 MB
    f16* A1p = (f16*)(ws + (1 << 20));        // h1: 1 MB
    int* bar = (int*)(ws + (2 << 20));        // barrier state

    (void)hipMemsetAsync(ws, 0, 2 << 20, stream);   // zero h parity planes
    (void)hipMemsetAsync(bar, 0, 256, stream);      // zero barrier

    lstm_persist<<<dim3(NBLK), dim3(256), 0, stream>>>(
        seq, Wih0, Whh0, bih0, bhh0, Wih1, Whh1, bih1, bhh1, linW, linb,
        A0p, A1p, outp, bar);
}